// Round 11
// baseline (567.805 us; speedup 1.0000x reference)
//
#include <hip/hip_runtime.h>

#define HSZ 32
#define TSEQ 2048
#define NBATCH 256

typedef float v2f __attribute__((ext_vector_type(2)));

__device__ __forceinline__ v2f make2(float a, float b) {
    v2f r; r.x = a; r.y = b; return r;
}

__device__ __forceinline__ float hw_exp2(float x) {
#if __has_builtin(__builtin_amdgcn_exp2f)
    return __builtin_amdgcn_exp2f(x);
#else
    return exp2f(x);
#endif
}

__device__ __forceinline__ float hw_rcp(float x) {
#if __has_builtin(__builtin_amdgcn_rcpf)
    return __builtin_amdgcn_rcpf(x);
#else
    return 1.0f / x;
#endif
}

#if __has_builtin(__builtin_elementwise_fma)
#define PKFMA(a, b, cc) __builtin_elementwise_fma((a), (b), (cc))
#else
__device__ __forceinline__ v2f PKFMA(v2f a, v2f b, v2f c) {
    return make2(fmaf(a.x, b.x, c.x), fmaf(a.y, b.y, c.y));
}
#endif

#define L2E 1.44269504088896340736f   // log2(e)

// Lockstep 2-element layout: lanes 0..31 = batch element A, lanes 32..63 =
// element B. Each lane owns ONE hidden unit (k = l&31) and computes all 4
// of its gates -> the c/h update is fully lane-local (no cross-lane gate
// exchange). h broadcast: trivial all-lane h_lds[l] write + 8 two-address
// broadcast float4 reads (2-way LDS broadcast is free). Weights are shared
// by both elements (same W), so the second chain costs only FMA issue --
// which fills R8's 189 idle cycles/step.
__global__ __launch_bounds__(64, 1) void lstm_last_kernel(
    const float* __restrict__ x,      // [B, T, 1]
    const float* __restrict__ W_ih,   // [4H, 1]
    const float* __restrict__ W_hh,   // [4H, H]
    const float* __restrict__ b_ih,   // [4H]
    const float* __restrict__ b_hh,   // [4H]
    float* __restrict__ out)          // [B, H]
{
    const int l    = threadIdx.x;   // 0..63
    const int k    = l & 31;        // hidden unit index
    const int half = l >> 5;        // 0: element A, 1: element B
    const int bA   = blockIdx.x;
    const int bB   = blockIdx.x + (NBATCH / 2);

    __shared__ float x_lds[2 * TSEQ + 4];   // [elem][t] + pad
    __shared__ float h_lds[64];             // [elem][k] == [l]

    // ---- one-time staging: both x rows into LDS (float4, coalesced) ----
    {
        const float4* xa = (const float4*)(x + (size_t)bA * TSEQ);
        const float4* xb = (const float4*)(x + (size_t)bB * TSEQ);
        float4* d0 = (float4*)x_lds;
        float4* d1 = (float4*)(x_lds + TSEQ);
        #pragma unroll
        for (int j = 0; j < 8; ++j) {
            d0[j * 64 + l] = xa[j * 64 + l];
            d1[j * 64 + l] = xb[j * 64 + l];
        }
    }
    h_lds[l] = 0.0f;   // h0 = 0

    // ---- one-time: my unit's 4 gate rows (i,f,g,o), j-paired, PRE-SCALED ----
    // sigmoid(d) = rcp(1+exp2(-L2E*d)); tanh(g) = 2*rcp(1+exp2(-2*L2E*g)) - 1.
    const float sI = -L2E;          // i, f, o rows
    const float sG = -2.0f * L2E;   // g rows
    v2f wi[16], wf[16], wg[16], wo[16];
    #pragma unroll
    for (int j = 0; j < HSZ; j += 4) {
        float4 ri = *(const float4*)(W_hh + (size_t)(k     ) * HSZ + j);
        float4 rf = *(const float4*)(W_hh + (size_t)(k + 32) * HSZ + j);
        float4 rg = *(const float4*)(W_hh + (size_t)(k + 64) * HSZ + j);
        float4 ro = *(const float4*)(W_hh + (size_t)(k + 96) * HSZ + j);
        wi[j/2] = make2(ri.x * sI, ri.y * sI);  wi[j/2+1] = make2(ri.z * sI, ri.w * sI);
        wf[j/2] = make2(rf.x * sI, rf.y * sI);  wf[j/2+1] = make2(rf.z * sI, rf.w * sI);
        wg[j/2] = make2(rg.x * sG, rg.y * sG);  wg[j/2+1] = make2(rg.z * sG, rg.w * sG);
        wo[j/2] = make2(ro.x * sI, ro.y * sI);  wo[j/2+1] = make2(ro.z * sI, ro.w * sI);
    }
    const float wxi = W_ih[k]      * sI, wxf = W_ih[k + 32] * sI;
    const float wxg = W_ih[k + 64] * sG, wxo = W_ih[k + 96] * sI;
    const float bi = (b_ih[k]      + b_hh[k]     ) * sI;
    const float bf = (b_ih[k + 32] + b_hh[k + 32]) * sI;
    const float bg = (b_ih[k + 64] + b_hh[k + 64]) * sG;
    const float bo = (b_ih[k + 96] + b_hh[k + 96]) * sI;

    // Carried cell state pre-scaled: cc = 2*L2E*c, so tanh(c) = 1-2*rcp(1+exp2(cc)).
    // c' = f*c + i*(2*r_g - 1)  =>  cc' = r_f*cc + r_i*(4*L2E*r_g - 2*L2E).
    const float GA = 4.0f * L2E, GB = -2.0f * L2E;

    float cc = 0.0f;
    float h  = 0.0f;

    const float*  xbase = x_lds + half * TSEQ;
    const float4* hb    = (const float4*)(h_lds + half * HSZ);

    __syncthreads();
    float xt = xbase[0];

    #pragma unroll 1
    for (int t = 0; t < TSEQ; ++t) {
        // ---- h broadcast read: 8x float4, 2 addresses (free broadcast).
        //      Same-wave DS pipe is in-order: sees last iteration's write. ----
        v2f hp[16];
        #pragma unroll
        for (int m = 0; m < 8; ++m) {
            float4 v4 = hb[m];
            hp[2*m]   = make2(v4.x, v4.y);
            hp[2*m+1] = make2(v4.z, v4.w);
        }

        // x-terms: no h dependency -> issue under the DS read latency
        float gxi = fmaf(wxi, xt, bi);
        float gxf = fmaf(wxf, xt, bf);
        float gxg = fmaf(wxg, xt, bg);
        float gxo = fmaf(wxo, xt, bo);
        float xtn = xbase[t + 1];       // prefetch

        // ---- 4 length-32 dots (this unit's i,f,g,o), 4 chains each ----
        v2f z = make2(0.f, 0.f);
        v2f ci0 = z, ci1 = z, ci2 = z, ci3 = z;
        v2f cf0 = z, cf1 = z, cf2 = z, cf3 = z;
        v2f cg0 = z, cg1 = z, cg2 = z, cg3 = z;
        v2f co0 = z, co1 = z, co2 = z, co3 = z;
        #pragma unroll
        for (int m = 0; m < 16; m += 4) {
            ci0 = PKFMA(wi[m],   hp[m],   ci0);
            ci1 = PKFMA(wi[m+1], hp[m+1], ci1);
            ci2 = PKFMA(wi[m+2], hp[m+2], ci2);
            ci3 = PKFMA(wi[m+3], hp[m+3], ci3);
            cf0 = PKFMA(wf[m],   hp[m],   cf0);
            cf1 = PKFMA(wf[m+1], hp[m+1], cf1);
            cf2 = PKFMA(wf[m+2], hp[m+2], cf2);
            cf3 = PKFMA(wf[m+3], hp[m+3], cf3);
            cg0 = PKFMA(wg[m],   hp[m],   cg0);
            cg1 = PKFMA(wg[m+1], hp[m+1], cg1);
            cg2 = PKFMA(wg[m+2], hp[m+2], cg2);
            cg3 = PKFMA(wg[m+3], hp[m+3], cg3);
            co0 = PKFMA(wo[m],   hp[m],   co0);
            co1 = PKFMA(wo[m+1], hp[m+1], co1);
            co2 = PKFMA(wo[m+2], hp[m+2], co2);
            co3 = PKFMA(wo[m+3], hp[m+3], co3);
        }
        v2f rvi = (ci0 + ci1) + (ci2 + ci3);
        v2f rvf = (cf0 + cf1) + (cf2 + cf3);
        v2f rvg = (cg0 + cg1) + (cg2 + cg3);
        v2f rvo = (co0 + co1) + (co2 + co3);
        float di  = (rvi.x + rvi.y) + gxi;   // pre-scaled
        float df  = (rvf.x + rvf.y) + gxf;
        float dg  = (rvg.x + rvg.y) + gxg;
        float do_ = (rvo.x + rvo.y) + gxo;

        // ---- activations: 5 exp2 + 3 rcp (combined-rcp sigmoid pairs) ----
        float ei = hw_exp2(di), ef = hw_exp2(df);
        float eg = hw_exp2(dg), eo = hw_exp2(do_);
        float ti = 1.0f + ei, tf = 1.0f + ef;
        float tg = 1.0f + eg, to = 1.0f + eo;
        float Rif = hw_rcp(ti * tf);
        float Rgo = hw_rcp(tg * to);
        float r_i = Rif * tf, r_f = Rif * ti;     // sigmoid(i), sigmoid(f)
        float r_g = Rgo * to, r_o = Rgo * tg;     // sigma(2g), sigmoid(o)

        // cc' = r_f*cc + r_i*(GA*r_g + GB)   (scaled cell update)
        float inner = fmaf(GA, r_g, GB);
        float cn = fmaf(r_f, cc, r_i * inner);
        cc = cn;

        // h = sigmoid(o) * tanh(c) = r_o - 2*r_o*rcp(1+exp2(cc'))
        float ec = hw_exp2(cn);
        float rc = hw_rcp(1.0f + ec);
        h = fmaf(-2.0f * r_o, rc, r_o);

        h_lds[l] = h;    // all 64 lanes write useful data
        xt = xtn;
    }

    out[(half ? bB : bA) * HSZ + k] = h;
}

extern "C" void kernel_launch(void* const* d_in, const int* in_sizes, int n_in,
                              void* d_out, int out_size, void* d_ws, size_t ws_size,
                              hipStream_t stream) {
    const float* x    = (const float*)d_in[0];
    const float* W_ih = (const float*)d_in[1];
    const float* W_hh = (const float*)d_in[2];
    const float* b_ih = (const float*)d_in[3];
    const float* b_hh = (const float*)d_in[4];
    float* out = (float*)d_out;

    lstm_last_kernel<<<NBATCH / 2, 64, 0, stream>>>(x, W_ih, W_hh, b_ih, b_hh, out);
}

// Round 12
// 557.213 us; speedup vs baseline: 1.0190x; 1.0190x over previous
//
#include <hip/hip_runtime.h>

#define HSZ 32
#define TSEQ 2048
#define NBATCH 256

typedef float v2f __attribute__((ext_vector_type(2)));
typedef unsigned int v2u __attribute__((ext_vector_type(2)));

__device__ __forceinline__ v2f make2(float a, float b) {
    v2f r; r.x = a; r.y = b; return r;
}

__device__ __forceinline__ float hw_exp2(float x) {
#if __has_builtin(__builtin_amdgcn_exp2f)
    return __builtin_amdgcn_exp2f(x);
#else
    return exp2f(x);
#endif
}

__device__ __forceinline__ float hw_rcp(float x) {
#if __has_builtin(__builtin_amdgcn_rcpf)
    return __builtin_amdgcn_rcpf(x);
#else
    return 1.0f / x;
#endif
}

// Direction-agnostic cross-half combine: returns v[lane&31] + v[(lane&31)+32]
// in ALL lanes. (Proven R2-R10.)
__device__ __forceinline__ float half_sum(float v) {
#if __has_builtin(__builtin_amdgcn_permlane32_swap)
    v2u r = __builtin_amdgcn_permlane32_swap(__float_as_uint(v), __float_as_uint(v), false, false);
    return __uint_as_float(r.x) + __uint_as_float(r.y);
#else
    return v + __shfl_xor(v, 32, 64);
#endif
}

#if __has_builtin(__builtin_elementwise_fma)
#define PKFMA(a, b, cc) __builtin_elementwise_fma((a), (b), (cc))
#else
__device__ __forceinline__ v2f PKFMA(v2f a, v2f b, v2f c) {
    return make2(fmaf(a.x, b.x, c.x), fmaf(a.y, b.y, c.y));
}
#endif

#define NL2E -1.44269504088896340736f   // -log2(e)
// Carried cell state is pre-scaled: cc = 2*log2e * c, so tanh(c) = 1 - 2*rcp(1+exp2(cc)).

__global__ __launch_bounds__(64, 1) void lstm_last_kernel(
    const float* __restrict__ x,      // [B, T, 1]
    const float* __restrict__ W_ih,   // [4H, 1]
    const float* __restrict__ W_hh,   // [4H, H]
    const float* __restrict__ b_ih,   // [4H]
    const float* __restrict__ b_hh,   // [4H]
    float* __restrict__ out)          // [B, H]
{
    const int b    = blockIdx.x;
    const int l    = threadIdx.x;   // 0..63
    const int k    = l & 31;        // hidden unit index
    const int half = l >> 5;        // 0: rows (i_k, g_k); 1: rows (f_k, o_k)
    const int row0 = l;             // i_k (half0) or f_k (half1)
    const int row1 = l + 64;        // g_k (half0) or o_k (half1)

    __shared__ float x_lds[TSEQ + 4];
    __shared__ float h_lds[64];     // slots 0..31 = h, slots 32..63 = half0 trash pad

    // ---- one-time staging: x row into LDS (float4, coalesced) ----
    const float4* xrow4 = (const float4*)(x + (size_t)b * TSEQ);
    float4* xl4 = (float4*)x_lds;
    #pragma unroll
    for (int j = 0; j < (TSEQ / 4) / 64; ++j)   // 8 iters
        xl4[j * 64 + l] = xrow4[j * 64 + l];
    if (l == 0) x_lds[TSEQ] = 0.0f;
    h_lds[l] = 0.0f;                // h0 = 0 (and zero the pad)

    // ---- one-time: weights as j-pairs, PRE-SCALED ----
    // dot0 (i/f): * -log2e  => sigmoid = rcp(1+exp2(d0))
    // dot1 g:     * -2log2e => sigma(2g) = rcp(1+exp2(d1));  dot1 o: * -log2e
    const float sc0 = NL2E;
    const float sc1 = half ? NL2E : 2.0f * NL2E;

    v2f wp0[HSZ/2], wp1[HSZ/2];
    #pragma unroll
    for (int j = 0; j < HSZ; j += 4) {
        float4 a  = *(const float4*)(W_hh + row0 * HSZ + j);
        float4 c4 = *(const float4*)(W_hh + row1 * HSZ + j);
        wp0[j/2]     = make2(a.x * sc0,  a.y * sc0);
        wp0[j/2 + 1] = make2(a.z * sc0,  a.w * sc0);
        wp1[j/2]     = make2(c4.x * sc1, c4.y * sc1);
        wp1[j/2 + 1] = make2(c4.z * sc1, c4.w * sc1);
    }
    const v2f wxp0   = make2(W_ih[row0] * sc0, 0.0f);
    const v2f wxp1   = make2(W_ih[row1] * sc1, 0.0f);
    const v2f biasp0 = make2((b_ih[row0] + b_hh[row0]) * sc0, 0.0f);
    const v2f biasp1 = make2((b_ih[row1] + b_hh[row1]) * sc1, 0.0f);

    // a1 (half0) = S*tanh(g), S = 2*log2e = -2*NL2E: a1 = 2S*sigma(2g) - S
    const float s1mul = half ? 1.0f : -4.0f * NL2E;
    const float s1add = half ? 0.0f :  2.0f * NL2E;

    float cc = 0.0f;   // scaled cell state: 2*log2e * c
    float hk = 0.0f;   // h_k valid in lanes 32..63

    // All-lane LDS write address: half1 -> real slot (l-32), half0 -> pad (l+32).
    const int waddr = l ^ 32;

    __syncthreads();   // x_lds + h_lds ready
    float xt = x_lds[0];

    #pragma unroll 2
    for (int t = 0; t < TSEQ; ++t) {
        // ---- broadcast h: 8x ds_read_b128, uniform address (no conflicts).
        //      Pairs land directly in VGPR pairs for pk_fma. Same-wave DS pipe
        //      is in-order: sees last iteration's write, no barrier needed. ----
        v2f hp[HSZ/2];
        #pragma unroll
        for (int m = 0; m < 8; ++m) {
            float4 v4 = ((const float4*)h_lds)[m];
            hp[2*m]   = make2(v4.x, v4.y);
            hp[2*m+1] = make2(v4.z, v4.w);
        }

        float xt_next = x_lds[t + 1];   // prefetch (fills part of the RT window)

        v2f xtp = make2(xt, xt);

        // ---- two length-32 dots as packed j-pairs, 4 chains each.
        //      Chains 1..3 start with pk_mul (no zero-init movs). ----
        v2f q0 = PKFMA(wxp0, xtp, biasp0);
        v2f u0 = PKFMA(wxp1, xtp, biasp1);
        v2f q1 = wp0[1] * hp[1];
        v2f q2 = wp0[2] * hp[2];
        v2f q3 = wp0[3] * hp[3];
        v2f u1 = wp1[1] * hp[1];
        v2f u2 = wp1[2] * hp[2];
        v2f u3 = wp1[3] * hp[3];
        q0 = PKFMA(wp0[0], hp[0], q0);
        u0 = PKFMA(wp1[0], hp[0], u0);
        #pragma unroll
        for (int m = 4; m < HSZ/2; m += 4) {
            q0 = PKFMA(wp0[m],   hp[m],   q0);
            q1 = PKFMA(wp0[m+1], hp[m+1], q1);
            q2 = PKFMA(wp0[m+2], hp[m+2], q2);
            q3 = PKFMA(wp0[m+3], hp[m+3], q3);
            u0 = PKFMA(wp1[m],   hp[m],   u0);
            u1 = PKFMA(wp1[m+1], hp[m+1], u1);
            u2 = PKFMA(wp1[m+2], hp[m+2], u2);
            u3 = PKFMA(wp1[m+3], hp[m+3], u3);
        }
        v2f r0 = (q0 + q1) + (q2 + q3);
        v2f r1 = (u0 + u1) + (u2 + u3);
        float d0 = r0.x + r0.y;   // i (half0) / f (half1), pre-scaled
        float d1 = r1.x + r1.y;   // g (half0) / o (half1), pre-scaled

        float a0 = hw_rcp(1.0f + hw_exp2(d0));                     // sigmoid(i/f)
        float a1 = fmaf(s1mul, hw_rcp(1.0f + hw_exp2(d1)), s1add); // S*tanh(g) / sigm(o)
        float m2a1 = -2.0f * a1;                                   // off-chain

        // half0 piece: i * (S*tanh(g)) = S*(i*g); half1 piece: f * cc_old.
        // Cross-half SUM = cc_new (= S*c_new) in every lane.
        float v  = a0 * (half ? cc : a1);
        float cn = half_sum(v);
        cc = cn;

        // tanh(c) = 1 - 2*rcp(1+exp2(cc));  hk = a1*tanh(c) = fma(-2a1, r, a1)
        float r = hw_rcp(1.0f + hw_exp2(cn));
        hk = fmaf(m2a1, r, a1);   // valid (o*tanh(c)) in lanes 32..63

        // all-lane write: half1 -> real slots, half0 -> pad (no exec churn)
        h_lds[waddr] = hk;

        xt = xt_next;
    }

    if (half) out[b * HSZ + k] = hk;
}

extern "C" void kernel_launch(void* const* d_in, const int* in_sizes, int n_in,
                              void* d_out, int out_size, void* d_ws, size_t ws_size,
                              hipStream_t stream) {
    const float* x    = (const float*)d_in[0];
    const float* W_ih = (const float*)d_in[1];
    const float* W_hh = (const float*)d_in[2];
    const float* b_ih = (const float*)d_in[3];
    const float* b_hh = (const float*)d_in[4];
    float* out = (float*)d_out;

    lstm_last_kernel<<<NBATCH, 64, 0, stream>>>(x, W_ih, W_hh, b_ih, b_hh, out);
}

// Round 13
// 384.681 us; speedup vs baseline: 1.4760x; 1.4485x over previous
//
#include <hip/hip_runtime.h>

#define HSZ 32
#define TSEQ 2048
#define NBATCH 256

typedef float v2f __attribute__((ext_vector_type(2)));
typedef unsigned int v2u __attribute__((ext_vector_type(2)));

__device__ __forceinline__ v2f make2(float a, float b) {
    v2f r; r.x = a; r.y = b; return r;
}

__device__ __forceinline__ float hw_exp2(float x) {
#if __has_builtin(__builtin_amdgcn_exp2f)
    return __builtin_amdgcn_exp2f(x);
#else
    return exp2f(x);
#endif
}

__device__ __forceinline__ float hw_rcp(float x) {
#if __has_builtin(__builtin_amdgcn_rcpf)
    return __builtin_amdgcn_rcpf(x);
#else
    return 1.0f / x;
#endif
}

// Direction-agnostic cross-half combine: returns v[lane&31] + v[(lane&31)+32]
// in ALL lanes, regardless of which way the swap moves halves. (Proven R2-R11.)
__device__ __forceinline__ float half_sum(float v) {
#if __has_builtin(__builtin_amdgcn_permlane32_swap)
    v2u r = __builtin_amdgcn_permlane32_swap(__float_as_uint(v), __float_as_uint(v), false, false);
    return __uint_as_float(r.x) + __uint_as_float(r.y);
#else
    return v + __shfl_xor(v, 32, 64);
#endif
}

#if __has_builtin(__builtin_elementwise_fma)
#define PKFMA(a, b, cc) __builtin_elementwise_fma((a), (b), (cc))
#else
__device__ __forceinline__ v2f PKFMA(v2f a, v2f b, v2f c) {
    return make2(fmaf(a.x, b.x, c.x), fmaf(a.y, b.y, c.y));
}
#endif

#define NL2E -1.44269504088896340736f   // -log2(e)
// Carried cell state is pre-scaled: cc = 2*log2e * c, so tanh(c) = 1 - 2*rcp(1+exp2(cc)).

__global__ __launch_bounds__(64, 1) void lstm_last_kernel(
    const float* __restrict__ x,      // [B, T, 1]
    const float* __restrict__ W_ih,   // [4H, 1]
    const float* __restrict__ W_hh,   // [4H, H]
    const float* __restrict__ b_ih,   // [4H]
    const float* __restrict__ b_hh,   // [4H]
    float* __restrict__ out)          // [B, H]
{
    const int b    = blockIdx.x;
    const int l    = threadIdx.x;   // 0..63
    const int k    = l & 31;        // hidden unit index
    const int half = l >> 5;        // 0: rows (i_k, g_k); 1: rows (f_k, o_k)
    const int row0 = l;             // i_k (half0) or f_k (half1)
    const int row1 = l + 64;        // g_k (half0) or o_k (half1)

    __shared__ float x_lds[TSEQ + 4];
    __shared__ float h_lds[64];     // slots 0..31 = h, slots 32..63 = half0 trash pad

    // ---- one-time staging: x row into LDS (float4, coalesced) ----
    const float4* xrow4 = (const float4*)(x + (size_t)b * TSEQ);
    float4* xl4 = (float4*)x_lds;
    #pragma unroll
    for (int j = 0; j < (TSEQ / 4) / 64; ++j)   // 8 iters
        xl4[j * 64 + l] = xrow4[j * 64 + l];
    if (l == 0) x_lds[TSEQ] = 0.0f;
    h_lds[l] = 0.0f;                // h0 = 0 (and zero the pad)

    // ---- one-time: weights as j-pairs, PRE-SCALED ----
    // dot0 (i/f): * -log2e          => sigmoid = rcp(1+exp2(d0))
    // dot1 g:     * -2log2e         => sigma(2g) = rcp(1+exp2(d1))
    // dot1 o:     * -log2e          => sigmoid
    const float sc0 = NL2E;
    const float sc1 = half ? NL2E : 2.0f * NL2E;

    v2f wp0[HSZ/2], wp1[HSZ/2];
    #pragma unroll
    for (int j = 0; j < HSZ; j += 4) {
        float4 a  = *(const float4*)(W_hh + row0 * HSZ + j);
        float4 c4 = *(const float4*)(W_hh + row1 * HSZ + j);
        wp0[j/2]     = make2(a.x * sc0,  a.y * sc0);
        wp0[j/2 + 1] = make2(a.z * sc0,  a.w * sc0);
        wp1[j/2]     = make2(c4.x * sc1, c4.y * sc1);
        wp1[j/2 + 1] = make2(c4.z * sc1, c4.w * sc1);
    }
    const v2f wxp0   = make2(W_ih[row0] * sc0, 0.0f);
    const v2f wxp1   = make2(W_ih[row1] * sc1, 0.0f);
    const v2f biasp0 = make2((b_ih[row0] + b_hh[row0]) * sc0, 0.0f);
    const v2f biasp1 = make2((b_ih[row1] + b_hh[row1]) * sc1, 0.0f);

    // a1 (half0) = S*tanh(g), S = 2*log2e = -2*NL2E: a1 = 2S*sigma(2g) - S
    const float s1mul = half ? 1.0f : -4.0f * NL2E;
    const float s1add = half ? 0.0f :  2.0f * NL2E;

    float cc = 0.0f;   // scaled cell state: 2*log2e * c
    float hk = 0.0f;   // h_k valid in lanes 32..63

    // All-lane LDS write address: half1 -> real slot (l-32), half0 -> pad (l+32).
    const int waddr = l ^ 32;

    __syncthreads();   // x_lds + h_lds ready
    float xt = x_lds[0];

    #pragma unroll 1
    for (int t = 0; t < TSEQ; ++t) {
        // ---- broadcast h: 8x ds_read_b128, uniform address (no conflicts).
        //      Pairs land directly in VGPR pairs for pk_fma (no movs, no SGPRs).
        //      Same-wave DS pipe is in-order: sees last iteration's write. ----
        v2f hp[HSZ/2];
        #pragma unroll
        for (int m = 0; m < 8; ++m) {
            float4 v4 = ((const float4*)h_lds)[m];
            hp[2*m]   = make2(v4.x, v4.y);
            hp[2*m+1] = make2(v4.z, v4.w);
        }

        float xt_next = x_lds[t + 1];   // prefetch

        v2f xtp = make2(xt, xt);

        // ---- two length-32 dots as packed j-pairs, 4 chains each ----
        v2f q0 = PKFMA(wxp0, xtp, biasp0);
        v2f q1 = make2(0.f, 0.f), q2 = make2(0.f, 0.f), q3 = make2(0.f, 0.f);
        v2f u0 = PKFMA(wxp1, xtp, biasp1);
        v2f u1 = make2(0.f, 0.f), u2 = make2(0.f, 0.f), u3 = make2(0.f, 0.f);
        #pragma unroll
        for (int m = 0; m < HSZ/2; m += 4) {
            q0 = PKFMA(wp0[m],   hp[m],   q0);
            q1 = PKFMA(wp0[m+1], hp[m+1], q1);
            q2 = PKFMA(wp0[m+2], hp[m+2], q2);
            q3 = PKFMA(wp0[m+3], hp[m+3], q3);
            u0 = PKFMA(wp1[m],   hp[m],   u0);
            u1 = PKFMA(wp1[m+1], hp[m+1], u1);
            u2 = PKFMA(wp1[m+2], hp[m+2], u2);
            u3 = PKFMA(wp1[m+3], hp[m+3], u3);
        }
        v2f r0 = (q0 + q1) + (q2 + q3);
        v2f r1 = (u0 + u1) + (u2 + u3);
        float d0 = r0.x + r0.y;   // i (half0) / f (half1), pre-scaled
        float d1 = r1.x + r1.y;   // g (half0) / o (half1), pre-scaled

        float a0 = hw_rcp(1.0f + hw_exp2(d0));                     // sigmoid(i/f)
        float a1 = fmaf(s1mul, hw_rcp(1.0f + hw_exp2(d1)), s1add); // S*tanh(g) / sigm(o)
        float m2a1 = -2.0f * a1;                                   // off-chain

        // half0 piece: i * (S*tanh(g)) = S*(i*g); half1 piece: f * cc_old.
        // Cross-half SUM = cc_new (= S*c_new) in every lane.
        float v  = a0 * (half ? cc : a1);
        float cn = half_sum(v);
        cc = cn;

        // tanh(c) = 1 - 2*rcp(1+exp2(cc));  hk = a1*tanh(c) = fma(-2a1, r, a1)
        float r = hw_rcp(1.0f + hw_exp2(cn));
        hk = fmaf(m2a1, r, a1);   // valid (o*tanh(c)) in lanes 32..63

        // all-lane write: half1 -> real slots, half0 -> pad (no exec churn)
        h_lds[waddr] = hk;

        xt = xt_next;
    }

    if (half) out[b * HSZ + k] = hk;
}

extern "C" void kernel_launch(void* const* d_in, const int* in_sizes, int n_in,
                              void* d_out, int out_size, void* d_ws, size_t ws_size,
                              hipStream_t stream) {
    const float* x    = (const float*)d_in[0];
    const float* W_ih = (const float*)d_in[1];
    const float* W_hh = (const float*)d_in[2];
    const float* b_ih = (const float*)d_in[3];
    const float* b_hh = (const float*)d_in[4];
    float* out = (float*)d_out;

    lstm_last_kernel<<<NBATCH, 64, 0, stream>>>(x, W_ih, W_hh, b_ih, b_hh, out);
}